// Round 1
// baseline (2027.612 us; speedup 1.0000x reference)
//
#include <hip/hip_runtime.h>
#include <math.h>

#define NB 8
#define NC 256
#define HWSZ 1024
#define NHEAD 8
#define DHEAD 32
#define NGRP 32
#define CPG 8
#define EPSV 1e-5f

// ---------------- GroupNorm stats: mean + rstd per (which, b, group) ----------------
__global__ void gn_stats_kernel(const float* __restrict__ xq,
                                const float* __restrict__ xkv,
                                float* __restrict__ stats) {
    int idx = blockIdx.x;            // which*256 + b*32 + g
    int which = idx >> 8;
    int b = (idx >> 5) & 7;
    int g = idx & 31;
    const float* x = which ? xkv : xq;
    const float4* xb = (const float4*)(x + ((size_t)(b * NC + g * CPG)) * HWSZ);
    float s = 0.f, ss = 0.f;
    for (int i = threadIdx.x; i < (CPG * HWSZ) / 4; i += 256) {
        float4 v = xb[i];
        s += v.x + v.y + v.z + v.w;
        ss += v.x * v.x + v.y * v.y + v.z * v.z + v.w * v.w;
    }
    #pragma unroll
    for (int off = 32; off > 0; off >>= 1) {
        s += __shfl_down(s, off);
        ss += __shfl_down(ss, off);
    }
    __shared__ float red[8];
    int wid = threadIdx.x >> 6;
    if ((threadIdx.x & 63) == 0) { red[wid * 2] = s; red[wid * 2 + 1] = ss; }
    __syncthreads();
    if (threadIdx.x == 0) {
        float S = red[0] + red[2] + red[4] + red[6];
        float SS = red[1] + red[3] + red[5] + red[7];
        float mean = S * (1.f / (CPG * HWSZ));
        float var = SS * (1.f / (CPG * HWSZ)) - mean * mean;
        stats[idx * 2] = mean;
        stats[idx * 2 + 1] = rsqrtf(var + EPSV);
    }
}

// ---------------- Projection GEMM: Y[o, b*1024+p] = sum_c W[o,c] * norm(X[b,c,p]) ----
// MODE 0: Q   (Co=256, plain [b][o][p] output)
// MODE 1: KV  (Co=512, split into k_buf / v_buf per-head layout)
// MODE 2: OUT (Co=256, no norm, + bias + residual, write d_out)
template<int MODE>
__global__ void proj_kernel(const float* __restrict__ Wm,
                            const float* __restrict__ X,
                            const float* __restrict__ stats,
                            const float* __restrict__ gscale,
                            const float* __restrict__ gbias,
                            const float* __restrict__ bias_out,
                            const float* __restrict__ resid,
                            float* __restrict__ out0,
                            float* __restrict__ out1) {
    __shared__ float Ws[32][68];   // [c][o], padded (16B-aligned rows, conflict-light)
    __shared__ float Xs[32][64];   // [c][p]
    const int p0 = blockIdx.x * 64;
    const int o0 = blockIdx.y * 64;
    const int b  = blockIdx.z;
    const int tid = threadIdx.x;
    const int tx = tid & 15, ty = tid >> 4;
    const float* Xb = X + (size_t)b * NC * HWSZ;
    float acc[4][4] = {};
    for (int c0 = 0; c0 < NC; c0 += 32) {
        __syncthreads();
        // W tile: 64 o x 32 c (transposed into LDS)
        #pragma unroll
        for (int it = 0; it < 2; ++it) {
            int i = tid + it * 256;          // 0..511 float4s
            int oo = i >> 3, c4 = i & 7;
            float4 w = *(const float4*)&Wm[(size_t)(o0 + oo) * NC + c0 + c4 * 4];
            Ws[c4 * 4 + 0][oo] = w.x;
            Ws[c4 * 4 + 1][oo] = w.y;
            Ws[c4 * 4 + 2][oo] = w.z;
            Ws[c4 * 4 + 3][oo] = w.w;
        }
        // X tile: 32 c x 64 p, normalized on the fly (MODE<2)
        #pragma unroll
        for (int it = 0; it < 2; ++it) {
            int i = tid + it * 256;
            int cc = i >> 4, p4 = i & 15;
            int c = c0 + cc;
            float4 v = *(const float4*)&Xb[(size_t)c * HWSZ + p0 + p4 * 4];
            if (MODE < 2) {
                int g = c >> 3;
                float mean = stats[(b * NGRP + g) * 2];
                float rstd = stats[(b * NGRP + g) * 2 + 1];
                float a = rstd * gscale[c];
                float bb = gbias[c] - mean * a;
                v.x = v.x * a + bb; v.y = v.y * a + bb;
                v.z = v.z * a + bb; v.w = v.w * a + bb;
            }
            *(float4*)&Xs[cc][p4 * 4] = v;
        }
        __syncthreads();
        #pragma unroll
        for (int kk = 0; kk < 32; ++kk) {
            float4 av = *(const float4*)&Ws[kk][ty * 4];
            float4 bv = *(const float4*)&Xs[kk][tx * 4];
            float a[4]  = {av.x, av.y, av.z, av.w};
            float bb[4] = {bv.x, bv.y, bv.z, bv.w};
            #pragma unroll
            for (int i = 0; i < 4; ++i)
                #pragma unroll
                for (int j = 0; j < 4; ++j)
                    acc[i][j] += a[i] * bb[j];
        }
    }
    #pragma unroll
    for (int i = 0; i < 4; ++i) {
        int o = o0 + ty * 4 + i;
        int p = p0 + tx * 4;
        float4 r = make_float4(acc[i][0], acc[i][1], acc[i][2], acc[i][3]);
        if (MODE == 0) {
            *(float4*)&out0[((size_t)b * NC + o) * HWSZ + p] = r;
        } else if (MODE == 1) {
            int n = o >> 6, rr = o & 63;
            float* dst = (rr < 32)
                ? &out0[(((size_t)b * NHEAD + n) * DHEAD + rr) * HWSZ + p]
                : &out1[(((size_t)b * NHEAD + n) * DHEAD + (rr - 32)) * HWSZ + p];
            *(float4*)dst = r;
        } else {
            size_t off = ((size_t)b * NC + o) * HWSZ + p;
            float bo = bias_out[o];
            float4 rs = *(const float4*)&resid[off];
            r.x += bo + rs.x; r.y += bo + rs.y;
            r.z += bo + rs.z; r.w += bo + rs.w;
            *(float4*)&out0[off] = r;
        }
    }
}

// ---------------- Flash-style attention: 1 query/thread, online softmax ----------------
__global__ void attn_kernel(const float* __restrict__ qb,
                            const float* __restrict__ kb,
                            const float* __restrict__ vb,
                            float* __restrict__ ob) {
    __shared__ float Ks[32][64];
    __shared__ float Vs[32][64];
    const int bn = blockIdx.y;
    const int pq = blockIdx.x * 256 + threadIdx.x;
    const size_t base = (size_t)bn * DHEAD * HWSZ;
    float q[DHEAD];
    #pragma unroll
    for (int d = 0; d < DHEAD; ++d) q[d] = qb[base + (size_t)d * HWSZ + pq] * 0.0625f;
    float acc[DHEAD] = {};
    float s[64];
    float m = -INFINITY, l = 0.f;
    for (int kt = 0; kt < 16; ++kt) {
        __syncthreads();
        #pragma unroll
        for (int j = 0; j < 8; ++j) {
            int idx = threadIdx.x + j * 256;
            int row = idx >> 6, col = idx & 63;
            Ks[row][col] = kb[base + (size_t)row * HWSZ + kt * 64 + col];
            Vs[row][col] = vb[base + (size_t)row * HWSZ + kt * 64 + col];
        }
        __syncthreads();
        #pragma unroll
        for (int k4 = 0; k4 < 16; ++k4) {
            float sx = 0.f, sy = 0.f, sz = 0.f, sw = 0.f;
            #pragma unroll
            for (int d = 0; d < DHEAD; ++d) {
                float4 kv = *(const float4*)&Ks[d][k4 * 4];
                float qd = q[d];
                sx += qd * kv.x; sy += qd * kv.y;
                sz += qd * kv.z; sw += qd * kv.w;
            }
            s[k4 * 4 + 0] = sx; s[k4 * 4 + 1] = sy;
            s[k4 * 4 + 2] = sz; s[k4 * 4 + 3] = sw;
        }
        float tm = s[0];
        #pragma unroll
        for (int k = 1; k < 64; ++k) tm = fmaxf(tm, s[k]);
        float mnew = fmaxf(m, tm);
        float corr = __expf(m - mnew);   // first iter: exp(-inf) = 0
        float lsum = 0.f;
        #pragma unroll
        for (int k = 0; k < 64; ++k) { s[k] = __expf(s[k] - mnew); lsum += s[k]; }
        l = l * corr + lsum;
        #pragma unroll
        for (int d = 0; d < DHEAD; ++d) {
            float a = 0.f;
            #pragma unroll
            for (int k4 = 0; k4 < 16; ++k4) {
                float4 v = *(const float4*)&Vs[d][k4 * 4];
                a += s[k4*4+0] * v.x + s[k4*4+1] * v.y
                   + s[k4*4+2] * v.z + s[k4*4+3] * v.w;
            }
            acc[d] = acc[d] * corr + a;
        }
        m = mnew;
    }
    float invl = 1.f / l;
    #pragma unroll
    for (int d = 0; d < DHEAD; ++d)
        ob[base + (size_t)d * HWSZ + pq] = acc[d] * invl;
}

extern "C" void kernel_launch(void* const* d_in, const int* in_sizes, int n_in,
                              void* d_out, int out_size, void* d_ws, size_t ws_size,
                              hipStream_t stream) {
    const float* input_q  = (const float*)d_in[0];
    const float* input_kv = (const float*)d_in[1];
    const float* gq_scale = (const float*)d_in[2];
    const float* gq_bias  = (const float*)d_in[3];
    const float* gkv_scale = (const float*)d_in[4];
    const float* gkv_bias  = (const float*)d_in[5];
    const float* Wq   = (const float*)d_in[6];
    const float* Wkv  = (const float*)d_in[7];
    const float* Wout = (const float*)d_in[8];
    const float* bout = (const float*)d_in[9];
    float* out = (float*)d_out;

    float* ws = (float*)d_ws;
    const size_t PLANE = (size_t)NB * NC * HWSZ;   // 2,097,152 floats
    float* stats = ws;                 // 1024 floats: [which][b][g][mean,rstd]
    float* qbuf = ws + 4096;
    float* kbuf = qbuf + PLANE;
    float* vbuf = kbuf + PLANE;
    float* obuf = vbuf + PLANE;

    gn_stats_kernel<<<512, 256, 0, stream>>>(input_q, input_kv, stats);
    proj_kernel<0><<<dim3(16, 4, 8), 256, 0, stream>>>(
        Wq, input_q, stats, gq_scale, gq_bias, nullptr, nullptr, qbuf, nullptr);
    proj_kernel<1><<<dim3(16, 8, 8), 256, 0, stream>>>(
        Wkv, input_kv, stats + 512, gkv_scale, gkv_bias, nullptr, nullptr, kbuf, vbuf);
    attn_kernel<<<dim3(4, 64), 256, 0, stream>>>(qbuf, kbuf, vbuf, obuf);
    proj_kernel<2><<<dim3(16, 4, 8), 256, 0, stream>>>(
        Wout, obuf, nullptr, nullptr, nullptr, bout, input_q, out, nullptr);
}

// Round 2
// 746.587 us; speedup vs baseline: 2.7158x; 2.7158x over previous
//
#include <hip/hip_runtime.h>
#include <math.h>

#define NB 8
#define NC 256
#define HWSZ 1024
#define NHEAD 8
#define DHEAD 32
#define NGRP 32
#define CPG 8
#define EPSV 1e-5f

// ---------------- GroupNorm stats: mean + rstd per (which, b, group) ----------------
__global__ void gn_stats_kernel(const float* __restrict__ xq,
                                const float* __restrict__ xkv,
                                float* __restrict__ stats) {
    int idx = blockIdx.x;            // which*256 + b*32 + g
    int which = idx >> 8;
    int b = (idx >> 5) & 7;
    int g = idx & 31;
    const float* x = which ? xkv : xq;
    const float4* xb = (const float4*)(x + ((size_t)(b * NC + g * CPG)) * HWSZ);
    float s = 0.f, ss = 0.f;
    for (int i = threadIdx.x; i < (CPG * HWSZ) / 4; i += 256) {
        float4 v = xb[i];
        s += v.x + v.y + v.z + v.w;
        ss += v.x * v.x + v.y * v.y + v.z * v.z + v.w * v.w;
    }
    #pragma unroll
    for (int off = 32; off > 0; off >>= 1) {
        s += __shfl_down(s, off);
        ss += __shfl_down(ss, off);
    }
    __shared__ float red[8];
    int wid = threadIdx.x >> 6;
    if ((threadIdx.x & 63) == 0) { red[wid * 2] = s; red[wid * 2 + 1] = ss; }
    __syncthreads();
    if (threadIdx.x == 0) {
        float S = red[0] + red[2] + red[4] + red[6];
        float SS = red[1] + red[3] + red[5] + red[7];
        float mean = S * (1.f / (CPG * HWSZ));
        float var = SS * (1.f / (CPG * HWSZ)) - mean * mean;
        stats[idx * 2] = mean;
        stats[idx * 2 + 1] = rsqrtf(var + EPSV);
    }
}

// ---------------- Projection GEMM: Y[o, b*1024+p] = sum_c W[o,c] * norm(X[b,c,p]) ----
template<int MODE>
__global__ void proj_kernel(const float* __restrict__ Wm,
                            const float* __restrict__ X,
                            const float* __restrict__ stats,
                            const float* __restrict__ gscale,
                            const float* __restrict__ gbias,
                            const float* __restrict__ bias_out,
                            const float* __restrict__ resid,
                            float* __restrict__ out0,
                            float* __restrict__ out1) {
    __shared__ float Ws[32][68];   // [c][o]
    __shared__ float Xs[32][64];   // [c][p]
    const int p0 = blockIdx.x * 64;
    const int o0 = blockIdx.y * 64;
    const int b  = blockIdx.z;
    const int tid = threadIdx.x;
    const int tx = tid & 15, ty = tid >> 4;
    const float* Xb = X + (size_t)b * NC * HWSZ;
    float acc[4][4] = {};
    for (int c0 = 0; c0 < NC; c0 += 32) {
        __syncthreads();
        #pragma unroll
        for (int it = 0; it < 2; ++it) {
            int i = tid + it * 256;
            int oo = i >> 3, c4 = i & 7;
            float4 w = *(const float4*)&Wm[(size_t)(o0 + oo) * NC + c0 + c4 * 4];
            Ws[c4 * 4 + 0][oo] = w.x;
            Ws[c4 * 4 + 1][oo] = w.y;
            Ws[c4 * 4 + 2][oo] = w.z;
            Ws[c4 * 4 + 3][oo] = w.w;
        }
        #pragma unroll
        for (int it = 0; it < 2; ++it) {
            int i = tid + it * 256;
            int cc = i >> 4, p4 = i & 15;
            int c = c0 + cc;
            float4 v = *(const float4*)&Xb[(size_t)c * HWSZ + p0 + p4 * 4];
            if (MODE < 2) {
                int g = c >> 3;
                float mean = stats[(b * NGRP + g) * 2];
                float rstd = stats[(b * NGRP + g) * 2 + 1];
                float a = rstd * gscale[c];
                float bb = gbias[c] - mean * a;
                v.x = v.x * a + bb; v.y = v.y * a + bb;
                v.z = v.z * a + bb; v.w = v.w * a + bb;
            }
            *(float4*)&Xs[cc][p4 * 4] = v;
        }
        __syncthreads();
        #pragma unroll
        for (int kk = 0; kk < 32; ++kk) {
            float4 av = *(const float4*)&Ws[kk][ty * 4];
            float4 bv = *(const float4*)&Xs[kk][tx * 4];
            float a[4]  = {av.x, av.y, av.z, av.w};
            float bb[4] = {bv.x, bv.y, bv.z, bv.w};
            #pragma unroll
            for (int i = 0; i < 4; ++i)
                #pragma unroll
                for (int j = 0; j < 4; ++j)
                    acc[i][j] += a[i] * bb[j];
        }
    }
    #pragma unroll
    for (int i = 0; i < 4; ++i) {
        int o = o0 + ty * 4 + i;
        int p = p0 + tx * 4;
        float4 r = make_float4(acc[i][0], acc[i][1], acc[i][2], acc[i][3]);
        if (MODE == 0) {
            *(float4*)&out0[((size_t)b * NC + o) * HWSZ + p] = r;
        } else if (MODE == 1) {
            int n = o >> 6, rr = o & 63;
            float* dst = (rr < 32)
                ? &out0[(((size_t)b * NHEAD + n) * DHEAD + rr) * HWSZ + p]
                : &out1[(((size_t)b * NHEAD + n) * DHEAD + (rr - 32)) * HWSZ + p];
            *(float4*)dst = r;
        } else {
            size_t off = ((size_t)b * NC + o) * HWSZ + p;
            float bo = bias_out[o];
            float4 rs = *(const float4*)&resid[off];
            r.x += bo + rs.x; r.y += bo + rs.y;
            r.z += bo + rs.z; r.w += bo + rs.w;
            *(float4*)&out0[off] = r;
        }
    }
}

// ---------------- Flash-style attention: 1 query/thread, online softmax ----------------
// All per-thread arrays compile-time indexed (fully unrolled) => stay in VGPRs.
__global__ __launch_bounds__(256) void attn_kernel(const float* __restrict__ qb,
                                                   const float* __restrict__ kb,
                                                   const float* __restrict__ vb,
                                                   float* __restrict__ ob) {
    __shared__ float Ks[32][64];
    __shared__ float Vs[32][64];
    const int bn = blockIdx.y;
    const int pq = blockIdx.x * 256 + threadIdx.x;
    const size_t base = (size_t)bn * DHEAD * HWSZ;
    // fold 1/sqrt(256) and log2(e) into q; do softmax in base-2
    const float qscale = 0.0625f * 1.44269504088896f;
    float q[DHEAD];
    #pragma unroll
    for (int d = 0; d < DHEAD; ++d) q[d] = qb[base + (size_t)d * HWSZ + pq] * qscale;
    float acc[DHEAD] = {};
    float s[64];
    float m = -INFINITY, l = 0.f;
    for (int kt = 0; kt < 16; ++kt) {
        __syncthreads();
        #pragma unroll
        for (int j = 0; j < 8; ++j) {
            int idx = threadIdx.x + j * 256;
            int row = idx >> 6, col = idx & 63;
            Ks[row][col] = kb[base + (size_t)row * HWSZ + kt * 64 + col];
            Vs[row][col] = vb[base + (size_t)row * HWSZ + kt * 64 + col];
        }
        __syncthreads();
        #pragma unroll
        for (int k4 = 0; k4 < 16; ++k4) {
            float sx = 0.f, sy = 0.f, sz = 0.f, sw = 0.f;
            #pragma unroll
            for (int d = 0; d < DHEAD; ++d) {
                float4 kv = *(const float4*)&Ks[d][k4 * 4];
                float qd = q[d];
                sx += qd * kv.x; sy += qd * kv.y;
                sz += qd * kv.z; sw += qd * kv.w;
            }
            s[k4 * 4 + 0] = sx; s[k4 * 4 + 1] = sy;
            s[k4 * 4 + 2] = sz; s[k4 * 4 + 3] = sw;
        }
        // max over the 64 scores (tree, fully unrolled)
        float tm = fmaxf(s[0], s[1]);
        #pragma unroll
        for (int k = 2; k < 64; ++k) tm = fmaxf(tm, s[k]);
        float mnew = fmaxf(m, tm);
        float corr = exp2f(m - mnew);   // first iter: 2^(-inf) = 0
        float lsum = 0.f;
        #pragma unroll
        for (int k = 0; k < 64; ++k) { s[k] = exp2f(s[k] - mnew); lsum += s[k]; }
        l = l * corr + lsum;
        #pragma unroll
        for (int d = 0; d < DHEAD; ++d) {
            float a = 0.f;
            #pragma unroll
            for (int k4 = 0; k4 < 16; ++k4) {
                float4 v = *(const float4*)&Vs[d][k4 * 4];
                a += s[k4*4+0] * v.x + s[k4*4+1] * v.y
                   + s[k4*4+2] * v.z + s[k4*4+3] * v.w;
            }
            acc[d] = acc[d] * corr + a;
        }
        m = mnew;
    }
    float invl = 1.f / l;
    #pragma unroll
    for (int d = 0; d < DHEAD; ++d)
        ob[base + (size_t)d * HWSZ + pq] = acc[d] * invl;
}

extern "C" void kernel_launch(void* const* d_in, const int* in_sizes, int n_in,
                              void* d_out, int out_size, void* d_ws, size_t ws_size,
                              hipStream_t stream) {
    const float* input_q  = (const float*)d_in[0];
    const float* input_kv = (const float*)d_in[1];
    const float* gq_scale = (const float*)d_in[2];
    const float* gq_bias  = (const float*)d_in[3];
    const float* gkv_scale = (const float*)d_in[4];
    const float* gkv_bias  = (const float*)d_in[5];
    const float* Wq   = (const float*)d_in[6];
    const float* Wkv  = (const float*)d_in[7];
    const float* Wout = (const float*)d_in[8];
    const float* bout = (const float*)d_in[9];
    float* out = (float*)d_out;

    float* ws = (float*)d_ws;
    const size_t PLANE = (size_t)NB * NC * HWSZ;
    float* stats = ws;
    float* qbuf = ws + 4096;
    float* kbuf = qbuf + PLANE;
    float* vbuf = kbuf + PLANE;
    float* obuf = vbuf + PLANE;

    gn_stats_kernel<<<512, 256, 0, stream>>>(input_q, input_kv, stats);
    proj_kernel<0><<<dim3(16, 4, 8), 256, 0, stream>>>(
        Wq, input_q, stats, gq_scale, gq_bias, nullptr, nullptr, qbuf, nullptr);
    proj_kernel<1><<<dim3(16, 8, 8), 256, 0, stream>>>(
        Wkv, input_kv, stats + 512, gkv_scale, gkv_bias, nullptr, nullptr, kbuf, vbuf);
    attn_kernel<<<dim3(4, 64), 256, 0, stream>>>(qbuf, kbuf, vbuf, obuf);
    proj_kernel<2><<<dim3(16, 4, 8), 256, 0, stream>>>(
        Wout, obuf, nullptr, nullptr, nullptr, bout, input_q, out, nullptr);
}

// Round 3
// 132.210 us; speedup vs baseline: 15.3363x; 5.6470x over previous
//
#include <hip/hip_runtime.h>
#include <math.h>

#define NB 8
#define NC 256
#define HWSZ 1024
#define NHEAD 8
#define DHEAD 32
#define NGRP 32
#define CPG 8
#define EPSV 1e-5f

typedef float f32x4 __attribute__((ext_vector_type(4)));
typedef short bf16x8 __attribute__((ext_vector_type(8)));

__device__ __forceinline__ unsigned short f2bf(float x) {
    unsigned u = __float_as_uint(x);
    return (unsigned short)((u + 0x7FFFu + ((u >> 16) & 1u)) >> 16);
}
__device__ __forceinline__ unsigned pk2(float a, float b) {
    unsigned ua = __float_as_uint(a), ub = __float_as_uint(b);
    unsigned lo = (ua + 0x7FFFu + ((ua >> 16) & 1u)) >> 16;
    unsigned hi = (ub + 0x7FFFu + ((ub >> 16) & 1u)) & 0xFFFF0000u;
    return lo | hi;
}

// ---------------- GroupNorm stats: mean + rstd per (which, b, group) ----------------
__global__ void gn_stats_kernel(const float* __restrict__ xq,
                                const float* __restrict__ xkv,
                                float* __restrict__ stats) {
    int idx = blockIdx.x;            // which*256 + b*32 + g
    int which = idx >> 8;
    int b = (idx >> 5) & 7;
    int g = idx & 31;
    const float* x = which ? xkv : xq;
    const float4* xb = (const float4*)(x + ((size_t)(b * NC + g * CPG)) * HWSZ);
    float s = 0.f, ss = 0.f;
    for (int i = threadIdx.x; i < (CPG * HWSZ) / 4; i += 256) {
        float4 v = xb[i];
        s += v.x + v.y + v.z + v.w;
        ss += v.x * v.x + v.y * v.y + v.z * v.z + v.w * v.w;
    }
    #pragma unroll
    for (int off = 32; off > 0; off >>= 1) {
        s += __shfl_down(s, off);
        ss += __shfl_down(ss, off);
    }
    __shared__ float red[8];
    int wid = threadIdx.x >> 6;
    if ((threadIdx.x & 63) == 0) { red[wid * 2] = s; red[wid * 2 + 1] = ss; }
    __syncthreads();
    if (threadIdx.x == 0) {
        float S = red[0] + red[2] + red[4] + red[6];
        float SS = red[1] + red[3] + red[5] + red[7];
        float mean = S * (1.f / (CPG * HWSZ));
        float var = SS * (1.f / (CPG * HWSZ)) - mean * mean;
        stats[idx * 2] = mean;
        stats[idx * 2 + 1] = rsqrtf(var + EPSV);
    }
}

// ---------------- Projection GEMM: Y[o, b*1024+p] = sum_c W[o,c] * norm(X[b,c,p]) ----
// MODE 0: Q   -> bf16 qbuf [b][n][p][d], scaled by 0.0625*log2(e)
// MODE 1: KV  -> K: bf16 kbuf [b][n][p][d];  V: bf16 vbuf [b][n][d][p]
// MODE 2: OUT -> f32, + bias + residual, write d_out
template<int MODE>
__global__ void proj_kernel(const float* __restrict__ Wm,
                            const float* __restrict__ X,
                            const float* __restrict__ stats,
                            const float* __restrict__ gscale,
                            const float* __restrict__ gbias,
                            const float* __restrict__ bias_out,
                            const float* __restrict__ resid,
                            void* __restrict__ out0,
                            void* __restrict__ out1) {
    __shared__ float Ws[32][68];   // [c][o]
    __shared__ float Xs[32][64];   // [c][p]
    __shared__ unsigned short T[64][72];  // transpose staging (bf16), 144B rows
    const int p0 = blockIdx.x * 64;
    const int o0 = blockIdx.y * 64;
    const int b  = blockIdx.z;
    const int tid = threadIdx.x;
    const int tx = tid & 15, ty = tid >> 4;
    const float* Xb = X + (size_t)b * NC * HWSZ;
    float acc[4][4] = {};
    for (int c0 = 0; c0 < NC; c0 += 32) {
        __syncthreads();
        #pragma unroll
        for (int it = 0; it < 2; ++it) {
            int i = tid + it * 256;
            int oo = i >> 3, c4 = i & 7;
            float4 w = *(const float4*)&Wm[(size_t)(o0 + oo) * NC + c0 + c4 * 4];
            Ws[c4 * 4 + 0][oo] = w.x;
            Ws[c4 * 4 + 1][oo] = w.y;
            Ws[c4 * 4 + 2][oo] = w.z;
            Ws[c4 * 4 + 3][oo] = w.w;
        }
        #pragma unroll
        for (int it = 0; it < 2; ++it) {
            int i = tid + it * 256;
            int cc = i >> 4, p4 = i & 15;
            int c = c0 + cc;
            float4 v = *(const float4*)&Xb[(size_t)c * HWSZ + p0 + p4 * 4];
            if (MODE < 2) {
                int g = c >> 3;
                float mean = stats[(b * NGRP + g) * 2];
                float rstd = stats[(b * NGRP + g) * 2 + 1];
                float a = rstd * gscale[c];
                float bb = gbias[c] - mean * a;
                v.x = v.x * a + bb; v.y = v.y * a + bb;
                v.z = v.z * a + bb; v.w = v.w * a + bb;
            }
            *(float4*)&Xs[cc][p4 * 4] = v;
        }
        __syncthreads();
        #pragma unroll
        for (int kk = 0; kk < 32; ++kk) {
            float4 av = *(const float4*)&Ws[kk][ty * 4];
            float4 bv = *(const float4*)&Xs[kk][tx * 4];
            float a[4]  = {av.x, av.y, av.z, av.w};
            float bb[4] = {bv.x, bv.y, bv.z, bv.w};
            #pragma unroll
            for (int i = 0; i < 4; ++i)
                #pragma unroll
                for (int j = 0; j < 4; ++j)
                    acc[i][j] += a[i] * bb[j];
        }
    }

    if (MODE == 0) {
        // scale, bf16, transpose via LDS -> qbuf [b][n][p][d]
        const float qs = 0.0625f * 1.44269504088896f;
        __syncthreads();
        #pragma unroll
        for (int i = 0; i < 4; i += 2)
            #pragma unroll
            for (int j = 0; j < 4; ++j)
                *(unsigned*)&T[tx * 4 + j][ty * 4 + i] =
                    pk2(acc[i][j] * qs, acc[i + 1][j] * qs);
        __syncthreads();
        int p = tid >> 2, seg = tid & 3;
        int n = (o0 >> 5) + (seg >> 1);
        int d0 = (seg & 1) * 16;
        unsigned short* dst = (unsigned short*)out0 +
            (((size_t)b * NHEAD + n) * HWSZ + p0 + p) * DHEAD + d0;
        *(uint4*)dst       = *(uint4*)&T[p][seg * 16];
        *(uint4*)(dst + 8) = *(uint4*)&T[p][seg * 16 + 8];
    } else if (MODE == 1) {
        // rows 0-31 = K (transpose -> kbuf [b][n][p][d]); rows 32-63 = V ([b][n][d][p])
        const int n = blockIdx.y;   // o0 = n*64
        __syncthreads();
        if (ty < 8) {
            #pragma unroll
            for (int i = 0; i < 4; i += 2)
                #pragma unroll
                for (int j = 0; j < 4; ++j)
                    *(unsigned*)&T[tx * 4 + j][ty * 4 + i] =
                        pk2(acc[i][j], acc[i + 1][j]);
        } else {
            #pragma unroll
            for (int i = 0; i < 4; ++i) {
                int d = ty * 4 + i - 32;
                ushort4 vv;
                vv.x = f2bf(acc[i][0]); vv.y = f2bf(acc[i][1]);
                vv.z = f2bf(acc[i][2]); vv.w = f2bf(acc[i][3]);
                *(ushort4*)((unsigned short*)out1 +
                    (((size_t)b * NHEAD + n) * DHEAD + d) * HWSZ + p0 + tx * 4) = vv;
            }
        }
        __syncthreads();
        if (tid < 128) {
            int p = tid >> 1, seg = tid & 1;
            unsigned short* dst = (unsigned short*)out0 +
                (((size_t)b * NHEAD + n) * HWSZ + p0 + p) * DHEAD + seg * 16;
            *(uint4*)dst       = *(uint4*)&T[p][seg * 16];
            *(uint4*)(dst + 8) = *(uint4*)&T[p][seg * 16 + 8];
        }
    } else {
        #pragma unroll
        for (int i = 0; i < 4; ++i) {
            int o = o0 + ty * 4 + i;
            int p = p0 + tx * 4;
            size_t off = ((size_t)b * NC + o) * HWSZ + p;
            float bo = bias_out[o];
            float4 rs = *(const float4*)&resid[off];
            float4 r = make_float4(acc[i][0] + bo + rs.x, acc[i][1] + bo + rs.y,
                                   acc[i][2] + bo + rs.z, acc[i][3] + bo + rs.w);
            *(float4*)&((float*)out0)[off] = r;
        }
    }
}

// ---------------- MFMA flash attention ----------------
// One wave = 16 queries x all 1024 keys. S^T = K·Q^T (16x16x32 MFMA, swapped
// operands so D col = query = lane&15). Online softmax; P staged in per-wave
// LDS tile; PV: O^T[d][q] = V[d][k]·P^T[k][q]. No barriers.
__global__ __launch_bounds__(256) void attn_mfma_kernel(
        const unsigned short* __restrict__ qb,
        const unsigned short* __restrict__ kb,
        const unsigned short* __restrict__ vb,
        float* __restrict__ ob) {
    __shared__ unsigned short Pl[4][16][40];   // per-wave P tile [q][k], 80B rows
    const int tid = threadIdx.x;
    const int w = tid >> 6, lane = tid & 63;
    const int l16 = lane & 15, g = lane >> 4;
    const int bn = blockIdx.y;
    const int qp = blockIdx.x * 64 + w * 16 + l16;

    bf16x8 qf = *(const bf16x8*)(qb + ((size_t)bn * HWSZ + qp) * DHEAD + g * 8);
    const unsigned short* kbase = kb + (size_t)bn * HWSZ * DHEAD;
    const unsigned short* vbase = vb + (size_t)bn * DHEAD * HWSZ;

    f32x4 acc0 = {0.f, 0.f, 0.f, 0.f}, acc1 = {0.f, 0.f, 0.f, 0.f};
    float m = -INFINITY, l = 0.f;
    unsigned short* Prow = &Pl[w][l16][0];
    const unsigned short* Prd = &Pl[w][l16][g * 8];

    for (int kt = 0; kt < 32; ++kt) {
        const unsigned short* kp = kbase + ((size_t)(kt * 32 + l16)) * DHEAD + g * 8;
        bf16x8 kfa = *(const bf16x8*)kp;
        bf16x8 kfb = *(const bf16x8*)(kp + 16 * DHEAD);
        f32x4 z = {0.f, 0.f, 0.f, 0.f};
        f32x4 s0 = __builtin_amdgcn_mfma_f32_16x16x32_bf16(kfa, qf, z, 0, 0, 0);
        f32x4 s1 = __builtin_amdgcn_mfma_f32_16x16x32_bf16(kfb, qf, z, 0, 0, 0);

        float tm = fmaxf(fmaxf(fmaxf(s0.x, s0.y), fmaxf(s0.z, s0.w)),
                         fmaxf(fmaxf(s1.x, s1.y), fmaxf(s1.z, s1.w)));
        tm = fmaxf(tm, __shfl_xor(tm, 16, 64));
        tm = fmaxf(tm, __shfl_xor(tm, 32, 64));
        float mnew = fmaxf(m, tm);
        float corr = exp2f(m - mnew);
        float p00 = exp2f(s0.x - mnew), p01 = exp2f(s0.y - mnew);
        float p02 = exp2f(s0.z - mnew), p03 = exp2f(s0.w - mnew);
        float p10 = exp2f(s1.x - mnew), p11 = exp2f(s1.y - mnew);
        float p12 = exp2f(s1.z - mnew), p13 = exp2f(s1.w - mnew);
        float lsum = ((p00 + p01) + (p02 + p03)) + ((p10 + p11) + (p12 + p13));
        lsum += __shfl_xor(lsum, 16, 64);
        lsum += __shfl_xor(lsum, 32, 64);
        l = l * corr + lsum;
        m = mnew;
        acc0 *= corr; acc1 *= corr;

        uint2 w0, w1;
        w0.x = pk2(p00, p01); w0.y = pk2(p02, p03);
        w1.x = pk2(p10, p11); w1.y = pk2(p12, p13);
        *(uint2*)(Prow + 4 * g)      = w0;   // keys 4g..4g+3
        *(uint2*)(Prow + 16 + 4 * g) = w1;   // keys 16+4g..

        bf16x8 pf = *(const bf16x8*)Prd;
        const unsigned short* vp = vbase + (size_t)l16 * HWSZ + kt * 32 + g * 8;
        bf16x8 va  = *(const bf16x8*)vp;
        bf16x8 vb8 = *(const bf16x8*)(vp + 16 * HWSZ);
        acc0 = __builtin_amdgcn_mfma_f32_16x16x32_bf16(va,  pf, acc0, 0, 0, 0);
        acc1 = __builtin_amdgcn_mfma_f32_16x16x32_bf16(vb8, pf, acc1, 0, 0, 0);
    }
    float invl = 1.f / l;
    #pragma unroll
    for (int r = 0; r < 4; ++r) {
        int d0 = 4 * g + r;
        ob[((size_t)bn * DHEAD + d0) * HWSZ + qp]      = acc0[r] * invl;
        ob[((size_t)bn * DHEAD + 16 + d0) * HWSZ + qp] = acc1[r] * invl;
    }
}

extern "C" void kernel_launch(void* const* d_in, const int* in_sizes, int n_in,
                              void* d_out, int out_size, void* d_ws, size_t ws_size,
                              hipStream_t stream) {
    const float* input_q  = (const float*)d_in[0];
    const float* input_kv = (const float*)d_in[1];
    const float* gq_scale = (const float*)d_in[2];
    const float* gq_bias  = (const float*)d_in[3];
    const float* gkv_scale = (const float*)d_in[4];
    const float* gkv_bias  = (const float*)d_in[5];
    const float* Wq   = (const float*)d_in[6];
    const float* Wkv  = (const float*)d_in[7];
    const float* Wout = (const float*)d_in[8];
    const float* bout = (const float*)d_in[9];
    float* out = (float*)d_out;

    char* w = (char*)d_ws;
    float* stats = (float*)w;                               // 4 KB
    unsigned short* qbuf = (unsigned short*)(w + 16384);    // 4 MB  [b][n][p][d]
    unsigned short* kbuf = qbuf + (size_t)NB * NC * HWSZ;   // 4 MB  [b][n][p][d]
    unsigned short* vbuf = kbuf + (size_t)NB * NC * HWSZ;   // 4 MB  [b][n][d][p]
    float* obuf = (float*)(w + 16384 + 3ull * 4194304);     // 8 MB  [b][c][p]

    gn_stats_kernel<<<512, 256, 0, stream>>>(input_q, input_kv, stats);
    proj_kernel<0><<<dim3(16, 4, 8), 256, 0, stream>>>(
        Wq, input_q, stats, gq_scale, gq_bias, nullptr, nullptr, qbuf, nullptr);
    proj_kernel<1><<<dim3(16, 8, 8), 256, 0, stream>>>(
        Wkv, input_kv, stats + 512, gkv_scale, gkv_bias, nullptr, nullptr, kbuf, vbuf);
    attn_mfma_kernel<<<dim3(16, 64), 256, 0, stream>>>(qbuf, kbuf, vbuf, obuf);
    proj_kernel<2><<<dim3(16, 4, 8), 256, 0, stream>>>(
        Wout, obuf, nullptr, nullptr, nullptr, bout, input_q, out, nullptr);
}

// Round 5
// 80.095 us; speedup vs baseline: 25.3152x; 1.6507x over previous
//
#include <hip/hip_runtime.h>
#include <hip/hip_bf16.h>
#include <math.h>
#include <string.h>

#define NB 8
#define NC 256
#define HWSZ 1024
#define NHEAD 8
#define DHEAD 32
#define NGRP 32
#define CPG 8
#define EPSV 1e-5f

typedef float f32x4 __attribute__((ext_vector_type(4)));
typedef short bf16x8 __attribute__((ext_vector_type(8)));

__device__ __forceinline__ unsigned pk2(float a, float b) {
    __hip_bfloat162 h = __float22bfloat162_rn(make_float2(a, b));
    unsigned r;
    memcpy(&r, &h, sizeof(r));
    return r;
}
__device__ __forceinline__ unsigned short f2bf(float x) {
    __hip_bfloat16 h = __float2bfloat16(x);
    unsigned short r;
    memcpy(&r, &h, sizeof(r));
    return r;
}

// ---------------- GroupNorm stats ----------------
__global__ void gn_stats_kernel(const float* __restrict__ xq,
                                const float* __restrict__ xkv,
                                float* __restrict__ stats) {
    int idx = blockIdx.x;            // which*256 + b*32 + g
    int which = idx >> 8;
    int b = (idx >> 5) & 7;
    int g = idx & 31;
    const float* x = which ? xkv : xq;
    const float4* xb = (const float4*)(x + ((size_t)(b * NC + g * CPG)) * HWSZ);
    float s = 0.f, ss = 0.f;
    for (int i = threadIdx.x; i < (CPG * HWSZ) / 4; i += 256) {
        float4 v = xb[i];
        s += v.x + v.y + v.z + v.w;
        ss += v.x * v.x + v.y * v.y + v.z * v.z + v.w * v.w;
    }
    #pragma unroll
    for (int off = 32; off > 0; off >>= 1) {
        s += __shfl_down(s, off);
        ss += __shfl_down(ss, off);
    }
    __shared__ float red[8];
    int wid = threadIdx.x >> 6;
    if ((threadIdx.x & 63) == 0) { red[wid * 2] = s; red[wid * 2 + 1] = ss; }
    __syncthreads();
    if (threadIdx.x == 0) {
        float S = red[0] + red[2] + red[4] + red[6];
        float SS = red[1] + red[3] + red[5] + red[7];
        float mean = S * (1.f / (CPG * HWSZ));
        float var = SS * (1.f / (CPG * HWSZ)) - mean * mean;
        stats[idx * 2] = mean;
        stats[idx * 2 + 1] = rsqrtf(var + EPSV);
    }
}

// ---------------- Weight convert: fp32 [o][c] -> bf16 [o][c]; Wq pre-scaled ----
__global__ void wconv_kernel(const float* __restrict__ Wq,
                             const float* __restrict__ Wkv,
                             const float* __restrict__ Wout,
                             unsigned short* __restrict__ wqb,
                             unsigned short* __restrict__ wkvb,
                             unsigned short* __restrict__ woutb) {
    int gid = blockIdx.x * 256 + threadIdx.x;   // 32768 threads, 8 floats each
    int i0 = gid * 8;
    const float* src; unsigned short* dst; int off; float sc = 1.f;
    if (i0 < 65536)       { src = Wq;   dst = wqb;   off = i0;          sc = 0.0625f * 1.44269504088896f; }
    else if (i0 < 196608) { src = Wkv;  dst = wkvb;  off = i0 - 65536; }
    else                  { src = Wout; dst = woutb; off = i0 - 196608; }
    float4 v0 = *(const float4*)&src[off];
    float4 v1 = *(const float4*)&src[off + 4];
    uint4 o;
    o.x = pk2(v0.x * sc, v0.y * sc); o.y = pk2(v0.z * sc, v0.w * sc);
    o.z = pk2(v1.x * sc, v1.y * sc); o.w = pk2(v1.z * sc, v1.w * sc);
    *(uint4*)&dst[off] = o;
}

// ---------------- Norm + bf16 + transpose: x fp32 [b][c][p] -> xn bf16 [b][p][c] ----
__global__ __launch_bounds__(256) void norm_t_kernel(
        const float* __restrict__ xq, const float* __restrict__ xkv,
        const float* __restrict__ stats,
        const float* __restrict__ sq, const float* __restrict__ bq,
        const float* __restrict__ skv, const float* __restrict__ bkv,
        unsigned short* __restrict__ xnq, unsigned short* __restrict__ xnkv) {
    __shared__ unsigned short T[64][72];   // [p][c], 144B rows
    const int bz = blockIdx.z;             // which*8 + b
    const int which = bz >> 3, b = bz & 7;
    const int c0 = blockIdx.y * 64, p0 = blockIdx.x * 64;
    const float* x  = which ? xkv : xq;
    const float* sc = which ? skv : sq;
    const float* bi = which ? bkv : bq;
    const float* st = stats + ((size_t)which * 256 + b * 32) * 2;
    const int tid = threadIdx.x;
    const int cb = tid >> 4, pb = tid & 15;
    float mm[4][4];
    #pragma unroll
    for (int u = 0; u < 4; ++u) {
        int c = c0 + cb * 4 + u;
        float4 v = *(const float4*)&x[((size_t)b * NC + c) * HWSZ + p0 + pb * 4];
        int gg = c >> 3;
        float mean = st[gg * 2], rstd = st[gg * 2 + 1];
        float a = rstd * sc[c];
        float bbv = bi[c] - mean * a;
        mm[u][0] = v.x * a + bbv; mm[u][1] = v.y * a + bbv;
        mm[u][2] = v.z * a + bbv; mm[u][3] = v.w * a + bbv;
    }
    #pragma unroll
    for (int v = 0; v < 4; ++v) {
        uint2 s2;
        s2.x = pk2(mm[0][v], mm[1][v]);
        s2.y = pk2(mm[2][v], mm[3][v]);
        *(uint2*)&T[pb * 4 + v][cb * 4] = s2;
    }
    __syncthreads();
    unsigned short* dst = (which ? xnkv : xnq) + (size_t)b * HWSZ * NC;
    #pragma unroll
    for (int it = 0; it < 2; ++it) {
        int i = tid + it * 256;
        int row = i >> 3, seg = i & 7;
        *(uint4*)&dst[(size_t)(p0 + row) * NC + c0 + seg * 8] = *(const uint4*)&T[row][seg * 8];
    }
}

// ---------------- MFMA GEMM over K=256, 64x64 tile, 4 waves ----------------
// MODE 0: Q  = Wq(A) x xnq(B)  -> qbuf bf16 [b][n][p][d]
// MODE 1: KV = Wkv(A) x xnkv(B)-> kbuf [b][n][p][d] (waves 0,1) / vbuf [b][n][d][p] (waves 2,3)
// MODE 2: OUT = obuf(A, rows p) x Wout(B, rows o) -> f32 d_out + bias + residual
template<int MODE>
__global__ __launch_bounds__(256) void gemm_kernel(
        const unsigned short* __restrict__ Abase,
        const unsigned short* __restrict__ Bbase,
        const float* __restrict__ bias_out,
        const float* __restrict__ resid,
        void* __restrict__ out0, void* __restrict__ out1) {
    __shared__ unsigned short As[64 * 256];
    __shared__ unsigned short Bs[64 * 256];
    const int tid = threadIdx.x;
    const int l16 = tid & 15, g = (tid >> 4) & 3, w = tid >> 6;
    const int o0 = blockIdx.y * 64;
    const size_t prow0 = (size_t)blockIdx.x * 64;
    const unsigned short* Asrc = (MODE < 2) ? (Abase + (size_t)o0 * NC) : (Abase + prow0 * NC);
    const unsigned short* Bsrc = (MODE < 2) ? (Bbase + prow0 * NC) : (Bbase + (size_t)o0 * NC);
    #pragma unroll
    for (int it = 0; it < 8; ++it) {
        int idx = tid + it * 256;
        int row = idx >> 5, seg = idx & 31;
        int ds = row * 256 + ((seg ^ (row & 7)) << 3);   // XOR-swizzled 16B units
        *(uint4*)&As[ds] = *(const uint4*)&Asrc[(size_t)row * NC + seg * 8];
        *(uint4*)&Bs[ds] = *(const uint4*)&Bsrc[(size_t)row * NC + seg * 8];
    }
    __syncthreads();
    f32x4 acc[4] = {};
    const int abase = (w * 16 + l16) * 256;
    const int asw = l16 & 7;
    #pragma unroll
    for (int kk = 0; kk < 8; ++kk) {
        const int koff = ((kk * 4 + g) ^ asw) << 3;
        bf16x8 a = *(const bf16x8*)&As[abase + koff];
        #pragma unroll
        for (int j = 0; j < 4; ++j) {
            bf16x8 b = *(const bf16x8*)&Bs[(j * 16 + l16) * 256 + koff];
            acc[j] = __builtin_amdgcn_mfma_f32_16x16x32_bf16(a, b, acc[j], 0, 0, 0);
        }
    }
    const int b = (int)(prow0 >> 10);
    const int pp = (int)(prow0 & 1023);
    if (MODE == 0) {
        int ob_ = o0 + 16 * w + 4 * g;
        int n = ob_ >> 5, d0 = ob_ & 31;
        unsigned short* dst = (unsigned short*)out0 + ((size_t)(b * NHEAD + n) * HWSZ) * DHEAD + d0;
        #pragma unroll
        for (int j = 0; j < 4; ++j) {
            int p = pp + 16 * j + l16;
            uint2 st;
            st.x = pk2(acc[j][0], acc[j][1]);
            st.y = pk2(acc[j][2], acc[j][3]);
            *(uint2*)&dst[(size_t)p * DHEAD] = st;
        }
    } else if (MODE == 1) {
        int n = o0 >> 6;
        int d0 = 16 * (w & 1) + 4 * g;
        if (w < 2) {   // K
            unsigned short* dst = (unsigned short*)out0 + ((size_t)(b * NHEAD + n) * HWSZ) * DHEAD + d0;
            #pragma unroll
            for (int j = 0; j < 4; ++j) {
                int p = pp + 16 * j + l16;
                uint2 st;
                st.x = pk2(acc[j][0], acc[j][1]);
                st.y = pk2(acc[j][2], acc[j][3]);
                *(uint2*)&dst[(size_t)p * DHEAD] = st;
            }
        } else {       // V -> [b][n][d][p]
            unsigned short* dst = (unsigned short*)out1 + ((size_t)(b * NHEAD + n) * DHEAD + d0) * HWSZ;
            #pragma unroll
            for (int j = 0; j < 4; ++j) {
                int p = pp + 16 * j + l16;
                #pragma unroll
                for (int r = 0; r < 4; ++r)
                    dst[(size_t)r * HWSZ + p] = f2bf(acc[j][r]);
            }
        }
    } else {
        int p_b = pp + 16 * w + 4 * g;
        #pragma unroll
        for (int j = 0; j < 4; ++j) {
            int o = o0 + 16 * j + l16;
            float bo = bias_out[o];
            size_t off = ((size_t)b * NC + o) * HWSZ + p_b;
            float4 rs = *(const float4*)&resid[off];
            float4 vst = make_float4(acc[j][0] + bo + rs.x, acc[j][1] + bo + rs.y,
                                     acc[j][2] + bo + rs.z, acc[j][3] + bo + rs.w);
            *(float4*)&((float*)out0)[off] = vst;
        }
    }
}

// ---------------- MFMA flash attention (bf16 out [b][p][c]) ----------------
__global__ __launch_bounds__(256) void attn_mfma_kernel(
        const unsigned short* __restrict__ qb,
        const unsigned short* __restrict__ kb,
        const unsigned short* __restrict__ vb,
        unsigned short* __restrict__ ob) {
    __shared__ unsigned short Pl[4][16][40];
    const int tid = threadIdx.x;
    const int w = tid >> 6, lane = tid & 63;
    const int l16 = lane & 15, g = lane >> 4;
    const int bn = blockIdx.y;
    const int qp = blockIdx.x * 64 + w * 16 + l16;

    bf16x8 qf = *(const bf16x8*)(qb + ((size_t)bn * HWSZ + qp) * DHEAD + g * 8);
    const unsigned short* kbase = kb + (size_t)bn * HWSZ * DHEAD;
    const unsigned short* vbase = vb + (size_t)bn * DHEAD * HWSZ;

    f32x4 acc0 = {0.f, 0.f, 0.f, 0.f}, acc1 = {0.f, 0.f, 0.f, 0.f};
    float m = -INFINITY, l = 0.f;
    unsigned short* Prow = &Pl[w][l16][0];
    const unsigned short* Prd = &Pl[w][l16][g * 8];

    for (int kt = 0; kt < 32; ++kt) {
        const unsigned short* kp = kbase + ((size_t)(kt * 32 + l16)) * DHEAD + g * 8;
        bf16x8 kfa = *(const bf16x8*)kp;
        bf16x8 kfb = *(const bf16x8*)(kp + 16 * DHEAD);
        f32x4 z = {0.f, 0.f, 0.f, 0.f};
        f32x4 s0 = __builtin_amdgcn_mfma_f32_16x16x32_bf16(kfa, qf, z, 0, 0, 0);
        f32x4 s1 = __builtin_amdgcn_mfma_f32_16x16x32_bf16(kfb, qf, z, 0, 0, 0);

        float tm = fmaxf(fmaxf(fmaxf(s0[0], s0[1]), fmaxf(s0[2], s0[3])),
                         fmaxf(fmaxf(s1[0], s1[1]), fmaxf(s1[2], s1[3])));
        tm = fmaxf(tm, __shfl_xor(tm, 16, 64));
        tm = fmaxf(tm, __shfl_xor(tm, 32, 64));
        // defer-max (T13): only rescale when the tile max grew past m+8
        if (!__all(tm <= m + 8.f)) {
            float mnew = fmaxf(m, tm);
            float corr = __builtin_amdgcn_exp2f(m - mnew);  // first tile: 2^-inf = 0
            acc0 *= corr; acc1 *= corr; l *= corr;
            m = mnew;
        }
        float p00 = __builtin_amdgcn_exp2f(s0[0] - m), p01 = __builtin_amdgcn_exp2f(s0[1] - m);
        float p02 = __builtin_amdgcn_exp2f(s0[2] - m), p03 = __builtin_amdgcn_exp2f(s0[3] - m);
        float p10 = __builtin_amdgcn_exp2f(s1[0] - m), p11 = __builtin_amdgcn_exp2f(s1[1] - m);
        float p12 = __builtin_amdgcn_exp2f(s1[2] - m), p13 = __builtin_amdgcn_exp2f(s1[3] - m);
        float lsum = ((p00 + p01) + (p02 + p03)) + ((p10 + p11) + (p12 + p13));
        lsum += __shfl_xor(lsum, 16, 64);
        lsum += __shfl_xor(lsum, 32, 64);
        l += lsum;

        uint2 w0, w1;
        w0.x = pk2(p00, p01); w0.y = pk2(p02, p03);
        w1.x = pk2(p10, p11); w1.y = pk2(p12, p13);
        *(uint2*)(Prow + 4 * g)      = w0;
        *(uint2*)(Prow + 16 + 4 * g) = w1;

        bf16x8 pf = *(const bf16x8*)Prd;
        const unsigned short* vp = vbase + (size_t)l16 * HWSZ + kt * 32 + g * 8;
        bf16x8 va  = *(const bf16x8*)vp;
        bf16x8 vb8 = *(const bf16x8*)(vp + 16 * HWSZ);
        acc0 = __builtin_amdgcn_mfma_f32_16x16x32_bf16(va,  pf, acc0, 0, 0, 0);
        acc1 = __builtin_amdgcn_mfma_f32_16x16x32_bf16(vb8, pf, acc1, 0, 0, 0);
    }
    float invl = 1.f / l;
    const int b = bn >> 3, n = bn & 7;
    unsigned short* dst = ob + ((size_t)b * HWSZ + qp) * NC + n * DHEAD;
    uint2 st0, st1;
    st0.x = pk2(acc0[0] * invl, acc0[1] * invl);
    st0.y = pk2(acc0[2] * invl, acc0[3] * invl);
    st1.x = pk2(acc1[0] * invl, acc1[1] * invl);
    st1.y = pk2(acc1[2] * invl, acc1[3] * invl);
    *(uint2*)&dst[4 * g]      = st0;
    *(uint2*)&dst[16 + 4 * g] = st1;
}

extern "C" void kernel_launch(void* const* d_in, const int* in_sizes, int n_in,
                              void* d_out, int out_size, void* d_ws, size_t ws_size,
                              hipStream_t stream) {
    const float* input_q  = (const float*)d_in[0];
    const float* input_kv = (const float*)d_in[1];
    const float* gq_scale = (const float*)d_in[2];
    const float* gq_bias  = (const float*)d_in[3];
    const float* gkv_scale = (const float*)d_in[4];
    const float* gkv_bias  = (const float*)d_in[5];
    const float* Wq   = (const float*)d_in[6];
    const float* Wkv  = (const float*)d_in[7];
    const float* Wout = (const float*)d_in[8];
    const float* bout = (const float*)d_in[9];
    float* out = (float*)d_out;

    char* ws = (char*)d_ws;
    float* stats = (float*)ws;                                    // 8 KB
    unsigned short* wqb   = (unsigned short*)(ws + 16384);        // 128 KB
    unsigned short* wkvb  = (unsigned short*)(ws + 16384 + 131072);        // 256 KB
    unsigned short* woutb = (unsigned short*)(ws + 16384 + 131072 + 262144); // 128 KB
    const size_t MB = 1024 * 1024;
    unsigned short* xnq  = (unsigned short*)(ws + 1 * MB);   // 4 MB  [b][p][c]
    unsigned short* xnkv = (unsigned short*)(ws + 5 * MB);   // 4 MB
    unsigned short* qbuf = (unsigned short*)(ws + 9 * MB);   // 4 MB  [b][n][p][d]
    unsigned short* kbuf = (unsigned short*)(ws + 13 * MB);  // 4 MB  [b][n][p][d]
    unsigned short* vbuf = (unsigned short*)(ws + 17 * MB);  // 4 MB  [b][n][d][p]
    unsigned short* obuf = (unsigned short*)(ws + 21 * MB);  // 4 MB  [b][p][c]

    gn_stats_kernel<<<512, 256, 0, stream>>>(input_q, input_kv, stats);
    wconv_kernel<<<128, 256, 0, stream>>>(Wq, Wkv, Wout, wqb, wkvb, woutb);
    norm_t_kernel<<<dim3(16, 4, 16), 256, 0, stream>>>(
        input_q, input_kv, stats, gq_scale, gq_bias, gkv_scale, gkv_bias, xnq, xnkv);
    gemm_kernel<0><<<dim3(128, 4), 256, 0, stream>>>(wqb, xnq, nullptr, nullptr, qbuf, nullptr);
    gemm_kernel<1><<<dim3(128, 8), 256, 0, stream>>>(wkvb, xnkv, nullptr, nullptr, kbuf, vbuf);
    attn_mfma_kernel<<<dim3(16, 64), 256, 0, stream>>>(qbuf, kbuf, vbuf, obuf);
    gemm_kernel<2><<<dim3(128, 4), 256, 0, stream>>>(obuf, woutb, bout, input_q, out, nullptr);
}